// Round 15
// baseline (307.172 us; speedup 1.0000x reference)
//
#include <hip/hip_runtime.h>
#include <stdint.h>

// Problem dims
#define BDIM 8
#define CDIM 32
#define NDIM 512
#define TDIM 168
#define KG   2048          // GEMM K = 4 slices * 512 nodes
#define NJ   43008         // 1344 (b,l) * 32 o   (column order jj = (b*168+l)*32 + o)
#define ALPHA_ 0.05f
#define BETA_  0.95f

typedef __attribute__((ext_vector_type(8))) short short8;
typedef __attribute__((ext_vector_type(4))) float f32x4;
typedef __attribute__((ext_vector_type(2))) float f2v;
typedef __attribute__((ext_vector_type(4))) unsigned short u16x4;

__device__ __forceinline__ unsigned short f2bf(float f) {
  union { float f; unsigned int u; } v; v.f = f;
  unsigned int r = v.u + 0x7fffu + ((v.u >> 16) & 1u);
  return (unsigned short)(r >> 16);
}
__device__ __forceinline__ float bf2f(unsigned short h) {
  union { unsigned int u; float f; } v; v.u = ((unsigned int)h) << 16;
  return v.f;
}
__device__ __forceinline__ void gload_lds16(const void* g, void* l) {
  __builtin_amdgcn_global_load_lds((const __attribute__((address_space(1))) void*)g,
                                   (__attribute__((address_space(3))) void*)l, 16, 0, 0);
}

// ---- fused prep+build (+ucat in block 512): row/col sums, normalized A/A' -> G2+Af ----
__global__ void gc_prep2(const float* __restrict__ adp,
                         const float* __restrict__ W1, const float* __restrict__ b1,
                         const float* __restrict__ W2, const float* __restrict__ b2,
                         float* __restrict__ Af, unsigned short* __restrict__ G2,
                         unsigned short* __restrict__ Ub, float* __restrict__ bias) {
  int t = threadIdx.x;
  if (blockIdx.x == 512) {   // ucat
    for (int idx = t; idx < 160 * 32; idx += 256) {
      int ko = idx >> 5, c = idx & 31, o = ko & 31, s = ko >> 5;
      float v;
      if (s == 0)      v = BETA_ * (W1[o * 96 + 32 + c] + ALPHA_ * W1[o * 96 + 64 + c]);
      else if (s == 1) v = BETA_ * BETA_ * W1[o * 96 + 64 + c];
      else if (s == 2) v = BETA_ * (W2[o * 96 + 32 + c] + ALPHA_ * W2[o * 96 + 64 + c]);
      else if (s == 3) v = BETA_ * BETA_ * W2[o * 96 + 64 + c];
      else             v = W1[o * 96 + c] + ALPHA_ * (W1[o * 96 + 32 + c] + W1[o * 96 + 64 + c])
                         + W2[o * 96 + c] + ALPHA_ * (W2[o * 96 + 32 + c] + W2[o * 96 + 64 + c]);
      Ub[idx] = f2bf(v);
    }
    if (t < 32) bias[t] = b1[t] + b2[t];
    return;
  }
  int v = blockIdx.x;
  float sA = 0.f, sB = 0.f;
  for (int w = t; w < NDIM; w += 256) { sA += adp[v * NDIM + w]; sB += adp[w * NDIM + v]; }
  __shared__ float red[2][256];
  red[0][t] = sA; red[1][t] = sB; __syncthreads();
  for (int s = 128; s > 0; s >>= 1) {
    if (t < s) { red[0][t] += red[0][t + s]; red[1][t] += red[1][t + s]; }
    __syncthreads();
  }
  float ra = 1.f / (1.f + red[0][0]);
  float rb = 1.f / (1.f + red[1][0]);
  for (int w = t; w < NDIM; w += 256) {
    float d = (v == w) ? 1.f : 0.f;
    float a  = (adp[v * NDIM + w] + d) * ra;   // A[v][w]
    float a2 = (adp[w * NDIM + v] + d) * rb;   // A'[v][w]
    Af[(size_t)v * NDIM + w] = a;
    Af[(size_t)NDIM * NDIM + (size_t)v * NDIM + w] = a2;
    G2[(size_t)(((0 * 64) + (w >> 3)) * 512 + v) * 8 + (w & 7)] = f2bf(a);
    G2[(size_t)(((2 * 64) + (w >> 3)) * 512 + v) * 8 + (w & 7)] = f2bf(a2);
  }
}

// ---- A^2 (slice 1) and A'^2 (slice 3) into G2; 512 blocks of 32x32 tiles ----
__global__ __launch_bounds__(256, 4) void gc_sq2(const float* __restrict__ Af,
                                                 unsigned short* __restrict__ G2) {
  int bid = blockIdx.x;
  int mat = bid >> 8, tile = bid & 255;
  int v0 = (tile >> 4) * 32, w0 = (tile & 15) * 32;
  const float* M = Af + (size_t)mat * NDIM * NDIM;
  __shared__ float T1[64][33];
  __shared__ float T2[64][33];
  int t = threadIdx.x;
  int ty = t >> 4, tx = t & 15;
  float a00 = 0.f, a01 = 0.f, a10 = 0.f, a11 = 0.f;
  for (int u0 = 0; u0 < NDIM; u0 += 64) {
    #pragma unroll
    for (int q = 0; q < 8; ++q) {
      int id = q * 256 + t;
      int c = id & 63, r = id >> 6;
      T1[c][r] = M[(size_t)(v0 + r) * NDIM + u0 + c];
      int u = id >> 5, w = id & 31;
      T2[u][w] = M[(size_t)(u0 + u) * NDIM + w0 + w];
    }
    __syncthreads();
    for (int u = 0; u < 64; ++u) {
      f2v a = *(const f2v*)&T1[u][ty * 2];
      f2v b = *(const f2v*)&T2[u][tx * 2];
      a00 += a[0] * b[0]; a01 += a[0] * b[1];
      a10 += a[1] * b[0]; a11 += a[1] * b[1];
    }
    __syncthreads();
  }
  int sl = mat ? 3 : 1;
  int v = v0 + ty * 2, w = w0 + tx * 2;
  size_t cb = (size_t)(sl * 64 + (w >> 3)) * 512;
  size_t cb1 = (size_t)(sl * 64 + ((w + 1) >> 3)) * 512;
  G2[(cb  + v    ) * 8 + (w & 7)]       = f2bf(a00);
  G2[(cb1 + v    ) * 8 + ((w + 1) & 7)] = f2bf(a01);
  G2[(cb  + v + 1) * 8 + (w & 7)]       = f2bf(a10);
  G2[(cb1 + v + 1) * 8 + ((w + 1) & 7)] = f2bf(a11);
}

// ---- channel-mix via MFMA, direct stores in (b,l,o)-major column order ----
// Pg[kbg 0..320)[jj][8w]; slices 0..3 = GEMM B-panel, slice 4 = identity residual.
// grid 1024 = 8 b * 32 wt(16 w) * 4 lq(42 l); 256 threads (4 waves)
__global__ __launch_bounds__(256, 2) void gc_mix6(const float* __restrict__ x,
    const unsigned short* __restrict__ Ub, unsigned short* __restrict__ Pg) {
  __shared__ __align__(16) unsigned short xs[26880];  // [42 ll][16 w'][40 c pad]
  int bid = blockIdx.x;
  int lq = bid & 3, wt = (bid >> 2) & 31, b = bid >> 7;
  int l0 = lq * 42, w0 = wt * 16;
  int tid = threadIdx.x, wv = tid >> 6, lane = tid & 63;
  int l15 = lane & 15, hi = lane >> 4;

  // stage x[b][:][w0..w0+16)[l0..l0+42) -> xs (coalesced reads, swizzled 2B writes)
  #pragma unroll 4
  for (int e = 0; e < 84; ++e) {
    int id = e * 256 + tid;
    int c = id / 672, rem = id - c * 672;
    int w = rem / 42, ll = rem - w * 42;
    float v = x[(size_t)((b * 32 + c) * 512 + w0 + w) * 168 + l0 + ll];
    xs[(ll * 16 + (w ^ (ll & 15))) * 40 + c] = f2bf(v);
  }
  __syncthreads();

  short8 uF[10];
  #pragma unroll
  for (int mt = 0; mt < 10; ++mt)
    uF[mt] = *(const short8*)(Ub + (size_t)(mt * 16 + l15) * 32 + hi * 8);

  for (int i = 0; i < 11; ++i) {
    int li = wv + 4 * i;
    if (li >= 42) break;
    int l = l0 + li;
    short8 xf = *(const short8*)&xs[(li * 16 + (l15 ^ (li & 15))) * 40 + hi * 8];
    size_t jbase = (size_t)(b * 168 + l) * 32;
    #pragma unroll
    for (int mt = 0; mt < 10; ++mt) {
      f32x4 z = {0.f, 0.f, 0.f, 0.f};
      f32x4 p = __builtin_amdgcn_mfma_f32_16x16x32_bf16(xf, uF[mt], z, 0, 0, 0);
      size_t kbg = (size_t)((mt >> 1) * 64 + wt * 2 + (hi >> 1));
      size_t jj = jbase + ((mt & 1) << 4) + l15;
      u16x4 pk = { f2bf(p[0]), f2bf(p[1]), f2bf(p[2]), f2bf(p[3]) };
      *(u16x4*)(Pg + (kbg * NJ + jj) * 8 + (hi & 1) * 4) = pk;
    }
  }
}

// ---- main GEMM: wave-split-K, BARRIER-FREE main loop ----
// C[512 n][43008 jj] = G[512][2048] * P. 672 blocks (2 mt * 336 jt), 512 threads
// = 8 waves (wm,wn,kw): output sub-tile 128x64, K-half kw (1024 = 32 BK-32 tiles).
// Each wave double-buffers its PRIVATE A panel (16KB) via global_load_lds and
// loads B fragments direct-to-register from L2 (r13-proven). Sync = wave-private
// counted vmcnt(16) + wave-local lgkmcnt(0) WAR fence. Waves fully desynced ->
// one wave's LDS reads overlap another's MFMA. kw-pairs reduce via LDS at end.
__global__ __launch_bounds__(512, 2) void gc_gemm14(const unsigned short* __restrict__ G2,
    const unsigned short* __restrict__ Pg, const float* __restrict__ bias,
    float* __restrict__ out) {
  int bid = blockIdx.x;
  int swz = (bid & 7) * 84 + (bid >> 3);   // XCD-chunked bijective swizzle (672 = 8*84)
  int mt = swz & 1, jt = swz >> 1;
  int n0 = mt * 256, jj0 = jt * 128;

  __shared__ __align__(16) unsigned short SH[65536];   // 128 KB: 8 waves x 16KB (2x8KB bufs)

  int tid = threadIdx.x, lane = tid & 63, wid = tid >> 6;
  int kw = wid >> 2, wm = (wid >> 1) & 1, wn = wid & 1;
  int l15 = lane & 15, hi = lane >> 4;
  unsigned short* myLDS = SH + wid * 8192;     // [buf 2][kb 4][row 128][8]

  // per-wave A staging: 8 x 16B chunks per K-32 tile (kb = i>>1, rows (i&1)*64+lane)
  auto stageA = [&](int tile, int buf) {
    size_t kbgBase = (size_t)(kw * 128 + tile * 4);
    #pragma unroll
    for (int i = 0; i < 8; ++i) {
      const unsigned short* src =
          G2 + ((kbgBase + (i >> 1)) * 512 + n0 + wm * 128 + (i & 1) * 64 + lane) * 8;
      gload_lds16(src, myLDS + buf * 4096 + ((i >> 1) * 128 + (i & 1) * 64 + lane) * 8);
    }
  };
  // per-lane B fragments straight from Pg (chunk layout is fragment-coalesced)
  auto loadB = [&](short8* bx, int tile) {
    #pragma unroll
    for (int nj = 0; nj < 4; ++nj)
      bx[nj] = *(const short8*)(Pg +
          ((size_t)(kw * 128 + tile * 4 + hi) * NJ + jj0 + wn * 64 + nj * 16 + l15) * 8);
  };

  f32x4 acc[8][4] = {};
  short8 bE[4], bO[4];

  // prologue (queue order matters for vmcnt counting): A0, BE0, A1, BO1
  stageA(0, 0);
  loadB(bE, 0);
  stageA(1, 1);
  loadB(bO, 1);

  for (int s = 0; s < 16; ++s) {
    int t = 2 * s;
    // ---- even half: tile t, buf0, bE ----
    asm volatile("s_waitcnt vmcnt(16)" ::: "memory");     // A(t) landed (wave-private)
    short8 aF[8];
    #pragma unroll
    for (int mi = 0; mi < 8; ++mi)
      aF[mi] = *(const short8*)&myLDS[(hi * 128 + mi * 16 + l15) * 8];
    asm volatile("s_waitcnt lgkmcnt(0)" ::: "memory");    // reads done -> WAR-safe re-stage
    if (s < 15) stageA(t + 2, 0);
    #pragma unroll
    for (int mi = 0; mi < 8; ++mi)
      #pragma unroll
      for (int nj = 0; nj < 4; ++nj)
        acc[mi][nj] = __builtin_amdgcn_mfma_f32_16x16x32_bf16(aF[mi], bE[nj], acc[mi][nj], 0, 0, 0);
    if (s < 15) loadB(bE, t + 2);

    // ---- odd half: tile t+1, buf1, bO ----
    if (s < 15) { asm volatile("s_waitcnt vmcnt(16)" ::: "memory"); }
    else        { asm volatile("s_waitcnt vmcnt(0)"  ::: "memory"); }
    short8 aG[8];
    #pragma unroll
    for (int mi = 0; mi < 8; ++mi)
      aG[mi] = *(const short8*)&myLDS[4096 + (hi * 128 + mi * 16 + l15) * 8];
    asm volatile("s_waitcnt lgkmcnt(0)" ::: "memory");
    if (s < 15) stageA(t + 3, 1);
    #pragma unroll
    for (int mi = 0; mi < 8; ++mi)
      #pragma unroll
      for (int nj = 0; nj < 4; ++nj)
        acc[mi][nj] = __builtin_amdgcn_mfma_f32_16x16x32_bf16(aG[mi], bO[nj], acc[mi][nj], 0, 0, 0);
    if (s < 15) loadB(bO, t + 3);
  }

  // ---- kw reduction: kw0 writes slab, kw1 adds (one LDS round-trip) ----
  __syncthreads();
  float* slab = (float*)SH;                    // 4 pairs x 128x64 f32 = 128KB exact
  int pair = wm * 2 + wn;
  if (kw == 0) {
    #pragma unroll
    for (int mi = 0; mi < 8; ++mi)
      #pragma unroll
      for (int nj = 0; nj < 4; ++nj)
        #pragma unroll
        for (int r = 0; r < 4; ++r)
          slab[pair * 8192 + (mi * 16 + hi * 4 + r) * 64 + nj * 16 + l15] = acc[mi][nj][r];
  }
  __syncthreads();
  if (kw == 1) {
    #pragma unroll
    for (int mi = 0; mi < 8; ++mi)
      #pragma unroll
      for (int nj = 0; nj < 4; ++nj)
        #pragma unroll
        for (int r = 0; r < 4; ++r)
          acc[mi][nj][r] += slab[pair * 8192 + (mi * 16 + hi * 4 + r) * 64 + nj * 16 + l15];
  }
  __syncthreads();

  // ---- epilogue: 4 slabs of 64 n; LDS transpose; out = C + P4 + bias ----
  int bl0 = jt * 4;                            // 4 consecutive (b,l), same b (168%4==0)
  int bq = bl0 / 168, l0g = bl0 - bq * 168;
  float* Cs = (float*)SH;                      // 64*132*4 = 33792 B
  int o = tid & 31, nl8 = (tid >> 5) & 7;
  float bs = bias[o];
  for (int s = 0; s < 4; ++s) {
    if (kw == 1 && wm == (s >> 1)) {
      int mio = (s & 1) * 4;
      #pragma unroll
      for (int mi = 0; mi < 4; ++mi)
        #pragma unroll
        for (int nj = 0; nj < 4; ++nj) {
          int row = mi * 16 + hi * 4;
          int col = wn * 64 + nj * 16 + l15;
          #pragma unroll
          for (int r = 0; r < 4; ++r)
            Cs[(row + r) * 132 + col] = acc[mio + mi][nj][r];
        }
    }
    __syncthreads();
    if (tid < 256) {
      int n_g0 = n0 + s * 64 + nl8 * 8;
      const unsigned short* p4c =
          Pg + (((size_t)256 + (n_g0 >> 3)) * NJ + (size_t)bl0 * 32 + o) * 8;
      short8 pv0 = *(const short8*)(p4c);
      short8 pv1 = *(const short8*)(p4c + 256);    // l+1 (jj stride 32 chunks)
      short8 pv2 = *(const short8*)(p4c + 512);    // l+2
      short8 pv3 = *(const short8*)(p4c + 768);    // l+3
      #pragma unroll
      for (int q = 0; q < 8; ++q) {
        int nr = nl8 * 8 + q;
        int n_g = n_g0 + q;
        float v0 = Cs[nr * 132 +  0 + o] + bf2f((unsigned short)pv0[q]) + bs;
        float v1 = Cs[nr * 132 + 32 + o] + bf2f((unsigned short)pv1[q]) + bs;
        float v2 = Cs[nr * 132 + 64 + o] + bf2f((unsigned short)pv2[q]) + bs;
        float v3 = Cs[nr * 132 + 96 + o] + bf2f((unsigned short)pv3[q]) + bs;
        f32x4 vv = {v0, v1, v2, v3};
        *(f32x4*)(out + ((size_t)(bq * 32 + o) * 512 + n_g) * 168 + l0g) = vv;
      }
    }
    __syncthreads();
  }
}

extern "C" void kernel_launch(void* const* d_in, const int* in_sizes, int n_in,
                              void* d_out, int out_size, void* d_ws, size_t ws_size,
                              hipStream_t stream) {
  const float* x   = (const float*)d_in[0];
  const float* adp = (const float*)d_in[1];
  const float* W1  = (const float*)d_in[2];
  const float* b1  = (const float*)d_in[3];
  const float* W2  = (const float*)d_in[4];
  const float* b2  = (const float*)d_in[5];
  float* out = (float*)d_out;

  char* w = (char*)d_ws;
  unsigned short* Pg  = (unsigned short*)(w);                  // 220,200,960 B (5 slices)
  unsigned short* G2  = (unsigned short*)(w + 220200960ULL);   //   2,097,152 B
  float* Af           = (float*)(w + 222298112ULL);            //   2,097,152 B
  unsigned short* Ub  = (unsigned short*)(w + 224399360ULL);   //      16,384 B (10,240 used)
  float* bias         = (float*)(w + 224415744ULL);            //         128 B
  if (ws_size < 224415872ULL) return;                          // need ~214 MiB

  gc_prep2<<<513, 256, 0, stream>>>(adp, W1, b1, W2, b2, Af, G2, Ub, bias);
  gc_sq2<<<512, 256, 0, stream>>>(Af, G2);
  gc_mix6<<<1024, 256, 0, stream>>>(x, Ub, Pg);
  gc_gemm14<<<672, 512, 0, stream>>>(G2, Pg, bias, out);
}

// Round 16
// 261.728 us; speedup vs baseline: 1.1736x; 1.1736x over previous
//
#include <hip/hip_runtime.h>
#include <stdint.h>

// Problem dims
#define BDIM 8
#define CDIM 32
#define NDIM 512
#define TDIM 168
#define KG   2048          // GEMM K = 4 slices * 512 nodes
#define NJ   43008         // 1344 (b,l) * 32 o   (column order jj = (b*168+l)*32 + o)
#define ALPHA_ 0.05f
#define BETA_  0.95f

typedef __attribute__((ext_vector_type(8))) short short8;
typedef __attribute__((ext_vector_type(4))) float f32x4;
typedef __attribute__((ext_vector_type(2))) float f2v;
typedef __attribute__((ext_vector_type(4))) unsigned short u16x4;

__device__ __forceinline__ unsigned short f2bf(float f) {
  union { float f; unsigned int u; } v; v.f = f;
  unsigned int r = v.u + 0x7fffu + ((v.u >> 16) & 1u);
  return (unsigned short)(r >> 16);
}
__device__ __forceinline__ float bf2f(unsigned short h) {
  union { unsigned int u; float f; } v; v.u = ((unsigned int)h) << 16;
  return v.f;
}
__device__ __forceinline__ void gload_lds16(const void* g, void* l) {
  __builtin_amdgcn_global_load_lds((const __attribute__((address_space(1))) void*)g,
                                   (__attribute__((address_space(3))) void*)l, 16, 0, 0);
}

// ---- fused prep+build (+ucat in block 512): row/col sums, normalized A/A' -> G2+Af ----
__global__ void gc_prep2(const float* __restrict__ adp,
                         const float* __restrict__ W1, const float* __restrict__ b1,
                         const float* __restrict__ W2, const float* __restrict__ b2,
                         float* __restrict__ Af, unsigned short* __restrict__ G2,
                         unsigned short* __restrict__ Ub, float* __restrict__ bias) {
  int t = threadIdx.x;
  if (blockIdx.x == 512) {   // ucat
    for (int idx = t; idx < 160 * 32; idx += 256) {
      int ko = idx >> 5, c = idx & 31, o = ko & 31, s = ko >> 5;
      float v;
      if (s == 0)      v = BETA_ * (W1[o * 96 + 32 + c] + ALPHA_ * W1[o * 96 + 64 + c]);
      else if (s == 1) v = BETA_ * BETA_ * W1[o * 96 + 64 + c];
      else if (s == 2) v = BETA_ * (W2[o * 96 + 32 + c] + ALPHA_ * W2[o * 96 + 64 + c]);
      else if (s == 3) v = BETA_ * BETA_ * W2[o * 96 + 64 + c];
      else             v = W1[o * 96 + c] + ALPHA_ * (W1[o * 96 + 32 + c] + W1[o * 96 + 64 + c])
                         + W2[o * 96 + c] + ALPHA_ * (W2[o * 96 + 32 + c] + W2[o * 96 + 64 + c]);
      Ub[idx] = f2bf(v);
    }
    if (t < 32) bias[t] = b1[t] + b2[t];
    return;
  }
  int v = blockIdx.x;
  float sA = 0.f, sB = 0.f;
  for (int w = t; w < NDIM; w += 256) { sA += adp[v * NDIM + w]; sB += adp[w * NDIM + v]; }
  __shared__ float red[2][256];
  red[0][t] = sA; red[1][t] = sB; __syncthreads();
  for (int s = 128; s > 0; s >>= 1) {
    if (t < s) { red[0][t] += red[0][t + s]; red[1][t] += red[1][t + s]; }
    __syncthreads();
  }
  float ra = 1.f / (1.f + red[0][0]);
  float rb = 1.f / (1.f + red[1][0]);
  for (int w = t; w < NDIM; w += 256) {
    float d = (v == w) ? 1.f : 0.f;
    float a  = (adp[v * NDIM + w] + d) * ra;   // A[v][w]
    float a2 = (adp[w * NDIM + v] + d) * rb;   // A'[v][w]
    Af[(size_t)v * NDIM + w] = a;
    Af[(size_t)NDIM * NDIM + (size_t)v * NDIM + w] = a2;
    G2[(size_t)(((0 * 64) + (w >> 3)) * 512 + v) * 8 + (w & 7)] = f2bf(a);
    G2[(size_t)(((2 * 64) + (w >> 3)) * 512 + v) * 8 + (w & 7)] = f2bf(a2);
  }
}

// ---- A^2 (slice 1) and A'^2 (slice 3) into G2; 512 blocks of 32x32 tiles ----
__global__ __launch_bounds__(256, 4) void gc_sq2(const float* __restrict__ Af,
                                                 unsigned short* __restrict__ G2) {
  int bid = blockIdx.x;
  int mat = bid >> 8, tile = bid & 255;
  int v0 = (tile >> 4) * 32, w0 = (tile & 15) * 32;
  const float* M = Af + (size_t)mat * NDIM * NDIM;
  __shared__ float T1[64][33];
  __shared__ float T2[64][33];
  int t = threadIdx.x;
  int ty = t >> 4, tx = t & 15;
  float a00 = 0.f, a01 = 0.f, a10 = 0.f, a11 = 0.f;
  for (int u0 = 0; u0 < NDIM; u0 += 64) {
    #pragma unroll
    for (int q = 0; q < 8; ++q) {
      int id = q * 256 + t;
      int c = id & 63, r = id >> 6;
      T1[c][r] = M[(size_t)(v0 + r) * NDIM + u0 + c];
      int u = id >> 5, w = id & 31;
      T2[u][w] = M[(size_t)(u0 + u) * NDIM + w0 + w];
    }
    __syncthreads();
    for (int u = 0; u < 64; ++u) {
      f2v a = *(const f2v*)&T1[u][ty * 2];
      f2v b = *(const f2v*)&T2[u][tx * 2];
      a00 += a[0] * b[0]; a01 += a[0] * b[1];
      a10 += a[1] * b[0]; a11 += a[1] * b[1];
    }
    __syncthreads();
  }
  int sl = mat ? 3 : 1;
  int v = v0 + ty * 2, w = w0 + tx * 2;
  size_t cb = (size_t)(sl * 64 + (w >> 3)) * 512;
  size_t cb1 = (size_t)(sl * 64 + ((w + 1) >> 3)) * 512;
  G2[(cb  + v    ) * 8 + (w & 7)]       = f2bf(a00);
  G2[(cb1 + v    ) * 8 + ((w + 1) & 7)] = f2bf(a01);
  G2[(cb  + v + 1) * 8 + (w & 7)]       = f2bf(a10);
  G2[(cb1 + v + 1) * 8 + ((w + 1) & 7)] = f2bf(a11);
}

// ---- channel-mix via MFMA, direct stores in (b,l,o)-major column order ----
// Pg[kbg 0..320)[jj][8w]; slices 0..3 = GEMM B-panel, slice 4 = identity residual.
// grid 1024 = 8 b * 32 wt(16 w) * 4 lq(42 l); 256 threads (4 waves)
__global__ __launch_bounds__(256, 2) void gc_mix6(const float* __restrict__ x,
    const unsigned short* __restrict__ Ub, unsigned short* __restrict__ Pg) {
  __shared__ __align__(16) unsigned short xs[26880];  // [42 ll][16 w'][40 c pad]
  int bid = blockIdx.x;
  int lq = bid & 3, wt = (bid >> 2) & 31, b = bid >> 7;
  int l0 = lq * 42, w0 = wt * 16;
  int tid = threadIdx.x, wv = tid >> 6, lane = tid & 63;
  int l15 = lane & 15, hi = lane >> 4;

  // stage x[b][:][w0..w0+16)[l0..l0+42) -> xs (coalesced reads, swizzled 2B writes)
  #pragma unroll 4
  for (int e = 0; e < 84; ++e) {
    int id = e * 256 + tid;
    int c = id / 672, rem = id - c * 672;
    int w = rem / 42, ll = rem - w * 42;
    float v = x[(size_t)((b * 32 + c) * 512 + w0 + w) * 168 + l0 + ll];
    xs[(ll * 16 + (w ^ (ll & 15))) * 40 + c] = f2bf(v);
  }
  __syncthreads();

  short8 uF[10];
  #pragma unroll
  for (int mt = 0; mt < 10; ++mt)
    uF[mt] = *(const short8*)(Ub + (size_t)(mt * 16 + l15) * 32 + hi * 8);

  for (int i = 0; i < 11; ++i) {
    int li = wv + 4 * i;
    if (li >= 42) break;
    int l = l0 + li;
    short8 xf = *(const short8*)&xs[(li * 16 + (l15 ^ (li & 15))) * 40 + hi * 8];
    size_t jbase = (size_t)(b * 168 + l) * 32;
    #pragma unroll
    for (int mt = 0; mt < 10; ++mt) {
      f32x4 z = {0.f, 0.f, 0.f, 0.f};
      f32x4 p = __builtin_amdgcn_mfma_f32_16x16x32_bf16(xf, uF[mt], z, 0, 0, 0);
      size_t kbg = (size_t)((mt >> 1) * 64 + wt * 2 + (hi >> 1));
      size_t jj = jbase + ((mt & 1) << 4) + l15;
      u16x4 pk = { f2bf(p[0]), f2bf(p[1]), f2bf(p[2]), f2bf(p[3]) };
      *(u16x4*)(Pg + (kbg * NJ + jj) * 8 + (hi & 1) * 4) = pk;
    }
  }
}

// ---- main GEMM (best-measured r9/r14 structure) ----
// C[512 n][43008 jj] = G[512][2048] * P; epilogue adds P4 + bias via LDS slab.
// BM=256 BN=128 BK=32, 256 threads = 4 waves (2M x 2N), wave tile 128x64.
// TRIPLE-buffered LDS (72KB, 2 blocks/CU): tile t+2 overwrites tile t-1's buffer
// (reads completed last iter) -> one counted vmcnt(6) + one s_barrier per K-tile.
__global__ __launch_bounds__(256, 2) void gc_gemm9b(const unsigned short* __restrict__ G2,
    const unsigned short* __restrict__ Pg, const float* __restrict__ bias,
    float* __restrict__ out) {
  int bid = blockIdx.x;
  int swz = (bid & 7) * 84 + (bid >> 3);   // XCD-chunked bijective swizzle (672 = 8*84)
  int mt = swz & 1, jt = swz >> 1;         // mt fastest: B-panel pair adjacent on same XCD
  int n0 = mt * 256, jj0 = jt * 128;

  __shared__ __align__(16) unsigned short SH[36864];   // 72 KB
  unsigned short* AbBase = SH;            // 3 bufs x [kb 4][n 256][8] = 3 x 8192
  unsigned short* BbBase = SH + 24576;    // 3 bufs x [kb 4][j 128][8] = 3 x 4096

  int tid = threadIdx.x, lane = tid & 63, wid = tid >> 6;
  int wm = wid >> 1, wn = wid & 1;
  int l15 = lane & 15, hi = lane >> 4;

  const unsigned short* srcA[4]; int dA[4];
  #pragma unroll
  for (int q = 0; q < 4; ++q) {
    int f = q * 256 + tid;                       // kb = f>>8, nloc = f&255
    srcA[q] = G2 + ((size_t)(f >> 8) * 512 + n0 + (f & 255)) * 8;
    dA[q] = f * 8;
  }
  const unsigned short* srcB[2]; int dB[2];
  #pragma unroll
  for (int q = 0; q < 2; ++q) {
    int g = q * 256 + tid;                       // kb = g>>7, jloc = g&127
    srcB[q] = Pg + ((size_t)(g >> 7) * NJ + jj0 + (g & 127)) * 8;
    dB[q] = g * 8;
  }
  const size_t strideA = 4 * 512 * 8;            // shorts per K-tile of 32
  const size_t strideB = (size_t)4 * NJ * 8;

  f32x4 acc[8][4] = {};

  // prologue: tiles 0 -> buf0, 1 -> buf1 (12 loads in flight)
  #pragma unroll
  for (int q = 0; q < 4; ++q) gload_lds16(srcA[q], AbBase + dA[q]);
  #pragma unroll
  for (int q = 0; q < 2; ++q) gload_lds16(srcB[q], BbBase + dB[q]);
  #pragma unroll
  for (int q = 0; q < 4; ++q) gload_lds16(srcA[q] + strideA, AbBase + 8192 + dA[q]);
  #pragma unroll
  for (int q = 0; q < 2; ++q) gload_lds16(srcB[q] + strideB, BbBase + 4096 + dB[q]);

  int aoffs = (wm * 128 + l15) * 8;
  int boffs = (wn * 64 + l15) * 8;

  int cur = 0;
  for (int t = 0; t < 64; ++t) {
    if (t < 63) { asm volatile("s_waitcnt vmcnt(6)" ::: "memory"); }
    else        { asm volatile("s_waitcnt vmcnt(0)" ::: "memory"); }
    __builtin_amdgcn_s_barrier();                // tile t (buf[cur]) staged by all waves

    if (t < 62) {                                // stage t+2 into buffer of tile t-1
      int nxt = cur - 1; if (nxt < 0) nxt = 2;
      #pragma unroll
      for (int q = 0; q < 4; ++q)
        gload_lds16(srcA[q] + (size_t)(t + 2) * strideA, AbBase + nxt * 8192 + dA[q]);
      #pragma unroll
      for (int q = 0; q < 2; ++q)
        gload_lds16(srcB[q] + (size_t)(t + 2) * strideB, BbBase + nxt * 4096 + dB[q]);
    }

    const unsigned short* ap = AbBase + cur * 8192;
    const unsigned short* bp = BbBase + cur * 4096;
    short8 aF[8], bF[4];
    #pragma unroll
    for (int mi = 0; mi < 8; ++mi)
      aF[mi] = *(const short8*)&ap[hi * 2048 + aoffs + mi * 128];
    #pragma unroll
    for (int nj = 0; nj < 4; ++nj)
      bF[nj] = *(const short8*)&bp[hi * 1024 + boffs + nj * 128];

    #pragma unroll
    for (int mi = 0; mi < 8; ++mi)
      #pragma unroll
      for (int nj = 0; nj < 4; ++nj)
        acc[mi][nj] = __builtin_amdgcn_mfma_f32_16x16x32_bf16(aF[mi], bF[nj], acc[mi][nj], 0, 0, 0);

    cur = cur + 1; if (cur == 3) cur = 0;
  }

  // ---- epilogue: 4 slabs of 64 n; LDS transpose; out = C + P4 + bias ----
  int bl0 = jt * 4;                              // 4 consecutive (b,l), same b (168%4==0)
  int bq = bl0 / 168, l0g = bl0 - bq * 168;
  float* Cs = (float*)SH;                        // 64*132*4 = 33.8KB <= 72KB
  int o = tid & 31, nl8 = tid >> 5;              // o 0..31, nl8 0..7
  float bs = bias[o];
  __syncthreads();
  for (int s = 0; s < 4; ++s) {
    if (wm == (s >> 1)) {
      int mio = (s & 1) * 4;
      #pragma unroll
      for (int mi = 0; mi < 4; ++mi)
        #pragma unroll
        for (int nj = 0; nj < 4; ++nj) {
          int row = mi * 16 + hi * 4;
          int col = wn * 64 + nj * 16 + l15;
          #pragma unroll
          for (int r = 0; r < 4; ++r)
            Cs[(row + r) * 132 + col] = acc[mio + mi][nj][r];
        }
    }
    __syncthreads();
    int n_g0 = n0 + s * 64 + nl8 * 8;
    const unsigned short* p4c =
        Pg + (((size_t)256 + (n_g0 >> 3)) * NJ + (size_t)bl0 * 32 + o) * 8;
    short8 pv0 = *(const short8*)(p4c);
    short8 pv1 = *(const short8*)(p4c + 256);    // l+1 (jj stride 32 chunks)
    short8 pv2 = *(const short8*)(p4c + 512);    // l+2
    short8 pv3 = *(const short8*)(p4c + 768);    // l+3
    #pragma unroll
    for (int q = 0; q < 8; ++q) {
      int nr = nl8 * 8 + q;
      int n_g = n_g0 + q;
      float v0 = Cs[nr * 132 +  0 + o] + bf2f((unsigned short)pv0[q]) + bs;
      float v1 = Cs[nr * 132 + 32 + o] + bf2f((unsigned short)pv1[q]) + bs;
      float v2 = Cs[nr * 132 + 64 + o] + bf2f((unsigned short)pv2[q]) + bs;
      float v3 = Cs[nr * 132 + 96 + o] + bf2f((unsigned short)pv3[q]) + bs;
      f32x4 vv = {v0, v1, v2, v3};
      *(f32x4*)(out + ((size_t)(bq * 32 + o) * 512 + n_g) * 168 + l0g) = vv;
    }
    __syncthreads();
  }
}

extern "C" void kernel_launch(void* const* d_in, const int* in_sizes, int n_in,
                              void* d_out, int out_size, void* d_ws, size_t ws_size,
                              hipStream_t stream) {
  const float* x   = (const float*)d_in[0];
  const float* adp = (const float*)d_in[1];
  const float* W1  = (const float*)d_in[2];
  const float* b1  = (const float*)d_in[3];
  const float* W2  = (const float*)d_in[4];
  const float* b2  = (const float*)d_in[5];
  float* out = (float*)d_out;

  char* w = (char*)d_ws;
  unsigned short* Pg  = (unsigned short*)(w);                  // 220,200,960 B (5 slices)
  unsigned short* G2  = (unsigned short*)(w + 220200960ULL);   //   2,097,152 B
  float* Af           = (float*)(w + 222298112ULL);            //   2,097,152 B
  unsigned short* Ub  = (unsigned short*)(w + 224399360ULL);   //      16,384 B (10,240 used)
  float* bias         = (float*)(w + 224415744ULL);            //         128 B
  if (ws_size < 224415872ULL) return;                          // need ~214 MiB

  gc_prep2<<<513, 256, 0, stream>>>(adp, W1, b1, W2, b2, Af, G2, Ub, bias);
  gc_sq2<<<512, 256, 0, stream>>>(Af, G2);
  gc_mix6<<<1024, 256, 0, stream>>>(x, Ub, Pg);
  gc_gemm9b<<<672, 256, 0, stream>>>(G2, Pg, bias, out);
}

// Round 17
// 197.380 us; speedup vs baseline: 1.5562x; 1.3260x over previous
//
#include <hip/hip_runtime.h>
#include <stdint.h>

// Problem dims
#define BDIM 8
#define CDIM 32
#define NDIM 512
#define TDIM 168
#define KG   2048          // GEMM K = 4 slices * 512 nodes
#define NJ   43008         // 1344 (b,l) * 32 o   (column order jj = (b*168+l)*32 + o)
#define ALPHA_ 0.05f
#define BETA_  0.95f

typedef __attribute__((ext_vector_type(8))) short short8;
typedef __attribute__((ext_vector_type(4))) float f32x4;
typedef __attribute__((ext_vector_type(2))) float f2v;
typedef __attribute__((ext_vector_type(4))) unsigned short u16x4;

__device__ __forceinline__ unsigned short f2bf(float f) {
  union { float f; unsigned int u; } v; v.f = f;
  unsigned int r = v.u + 0x7fffu + ((v.u >> 16) & 1u);
  return (unsigned short)(r >> 16);
}
__device__ __forceinline__ float bf2f(unsigned short h) {
  union { unsigned int u; float f; } v; v.u = ((unsigned int)h) << 16;
  return v.f;
}
// OCP e4m3fn software encoder (RNE in normal range; used by prep/sq, fallback for mix)
__device__ __forceinline__ unsigned char f2fp8(float f) {
  union { float f; unsigned u; } v; v.f = f;
  unsigned s = (v.u >> 24) & 0x80u;
  unsigned au = v.u & 0x7fffffffu;
  if (au >= 0x43e80000u) return (unsigned char)(s | 0x7eu);   // >= 464 -> clamp to 448
  if (au < 0x3c800000u) {                                     // < 2^-6: subnormal (step 2^-9)
    float a = (f < 0.f) ? -f : f;
    unsigned m = (unsigned)(a * 512.f + 0.5f);
    return (unsigned char)(s | (m > 7 ? 8u : m));
  }
  unsigned e8 = au >> 23;
  unsigned m23 = au & 0x7fffffu;
  unsigned rm = m23 + 0x7ffffu + ((m23 >> 20) & 1u);
  if (rm >= 0x800000u) { rm -= 0x800000u; e8 += 1u; }
  unsigned e4 = e8 - 120u;                                    // in [1,15]
  return (unsigned char)(s | (e4 << 3) | (rm >> 20));
}
__device__ __forceinline__ unsigned int pack4fp8(float a, float b, float c, float d) {
#if __has_builtin(__builtin_amdgcn_cvt_pk_fp8_f32)
  int r = __builtin_amdgcn_cvt_pk_fp8_f32(a, b, 0, false);
  r = __builtin_amdgcn_cvt_pk_fp8_f32(c, d, r, true);
  return (unsigned int)r;
#else
  return (unsigned)f2fp8(a) | ((unsigned)f2fp8(b) << 8) |
         ((unsigned)f2fp8(c) << 16) | ((unsigned)f2fp8(d) << 24);
#endif
}
__device__ __forceinline__ void gload_lds16(const void* g, void* l) {
  __builtin_amdgcn_global_load_lds((const __attribute__((address_space(1))) void*)g,
                                   (__attribute__((address_space(3))) void*)l, 16, 0, 0);
}

// ---- fused prep+build (+ucat in block 512): G2f = fp8(A|A' * 64), chunks [k>>4][n][16] ----
__global__ void gc_prep2(const float* __restrict__ adp,
                         const float* __restrict__ W1, const float* __restrict__ b1,
                         const float* __restrict__ W2, const float* __restrict__ b2,
                         float* __restrict__ Af, unsigned char* __restrict__ G2f,
                         unsigned short* __restrict__ Ub, float* __restrict__ bias) {
  int t = threadIdx.x;
  if (blockIdx.x == 512) {   // ucat
    for (int idx = t; idx < 160 * 32; idx += 256) {
      int ko = idx >> 5, c = idx & 31, o = ko & 31, s = ko >> 5;
      float v;
      if (s == 0)      v = BETA_ * (W1[o * 96 + 32 + c] + ALPHA_ * W1[o * 96 + 64 + c]);
      else if (s == 1) v = BETA_ * BETA_ * W1[o * 96 + 64 + c];
      else if (s == 2) v = BETA_ * (W2[o * 96 + 32 + c] + ALPHA_ * W2[o * 96 + 64 + c]);
      else if (s == 3) v = BETA_ * BETA_ * W2[o * 96 + 64 + c];
      else             v = W1[o * 96 + c] + ALPHA_ * (W1[o * 96 + 32 + c] + W1[o * 96 + 64 + c])
                         + W2[o * 96 + c] + ALPHA_ * (W2[o * 96 + 32 + c] + W2[o * 96 + 64 + c]);
      Ub[idx] = f2bf(v);
    }
    if (t < 32) bias[t] = b1[t] + b2[t];
    return;
  }
  int v = blockIdx.x;
  float sA = 0.f, sB = 0.f;
  for (int w = t; w < NDIM; w += 256) { sA += adp[v * NDIM + w]; sB += adp[w * NDIM + v]; }
  __shared__ float red[2][256];
  red[0][t] = sA; red[1][t] = sB; __syncthreads();
  for (int s = 128; s > 0; s >>= 1) {
    if (t < s) { red[0][t] += red[0][t + s]; red[1][t] += red[1][t + s]; }
    __syncthreads();
  }
  float ra = 1.f / (1.f + red[0][0]);
  float rb = 1.f / (1.f + red[1][0]);
  for (int w = t; w < NDIM; w += 256) {
    float d = (v == w) ? 1.f : 0.f;
    float a  = (adp[v * NDIM + w] + d) * ra;   // A[v][w]
    float a2 = (adp[w * NDIM + v] + d) * rb;   // A'[v][w]
    Af[(size_t)v * NDIM + w] = a;
    Af[(size_t)NDIM * NDIM + (size_t)v * NDIM + w] = a2;
    // slice 0 chunks [0,32), slice 2 chunks [64,96); prescale x64 (undone in GEMM epilogue)
    G2f[((size_t)((0  + (w >> 4)) * 512) + v) * 16 + (w & 15)] = f2fp8(a * 64.f);
    G2f[((size_t)((64 + (w >> 4)) * 512) + v) * 16 + (w & 15)] = f2fp8(a2 * 64.f);
  }
}

// ---- A^2 (slice 1, chunks [32,64)) and A'^2 (slice 3, chunks [96,128)) into G2f ----
__global__ __launch_bounds__(256, 4) void gc_sq2(const float* __restrict__ Af,
                                                 unsigned char* __restrict__ G2f) {
  int bid = blockIdx.x;
  int mat = bid >> 8, tile = bid & 255;
  int v0 = (tile >> 4) * 32, w0 = (tile & 15) * 32;
  const float* M = Af + (size_t)mat * NDIM * NDIM;
  __shared__ float T1[64][33];
  __shared__ float T2[64][33];
  int t = threadIdx.x;
  int ty = t >> 4, tx = t & 15;
  float a00 = 0.f, a01 = 0.f, a10 = 0.f, a11 = 0.f;
  for (int u0 = 0; u0 < NDIM; u0 += 64) {
    #pragma unroll
    for (int q = 0; q < 8; ++q) {
      int id = q * 256 + t;
      int c = id & 63, r = id >> 6;
      T1[c][r] = M[(size_t)(v0 + r) * NDIM + u0 + c];
      int u = id >> 5, w = id & 31;
      T2[u][w] = M[(size_t)(u0 + u) * NDIM + w0 + w];
    }
    __syncthreads();
    for (int u = 0; u < 64; ++u) {
      f2v a = *(const f2v*)&T1[u][ty * 2];
      f2v b = *(const f2v*)&T2[u][tx * 2];
      a00 += a[0] * b[0]; a01 += a[0] * b[1];
      a10 += a[1] * b[0]; a11 += a[1] * b[1];
    }
    __syncthreads();
  }
  int base = mat ? 96 : 32;                    // slice 1 or 3 chunk base
  int v = v0 + ty * 2, w = w0 + tx * 2;
  size_t cb  = (size_t)((base + (w >> 4)) * 512) * 16;
  size_t cb1 = (size_t)((base + ((w + 1) >> 4)) * 512) * 16;
  G2f[cb  + (size_t)(v    ) * 16 + (w & 15)]       = f2fp8(a00 * 64.f);
  G2f[cb1 + (size_t)(v    ) * 16 + ((w + 1) & 15)] = f2fp8(a01 * 64.f);
  G2f[cb  + (size_t)(v + 1) * 16 + (w & 15)]       = f2fp8(a10 * 64.f);
  G2f[cb1 + (size_t)(v + 1) * 16 + ((w + 1) & 15)] = f2fp8(a11 * 64.f);
}

// ---- channel-mix via MFMA: fp8 Pgf (slices 0..3) + bf16 R0 (identity residual) ----
// Pgf[c16 0..128)[jj][16 fp8], c16 = slice*32 + (w>>4); R0[c8 0..64)[jj][8 bf16].
// grid 1024 = 8 b * 32 wt(16 w) * 4 lq(42 l); 256 threads (4 waves)
__global__ __launch_bounds__(256, 2) void gc_mix6(const float* __restrict__ x,
    const unsigned short* __restrict__ Ub, unsigned char* __restrict__ Pgf,
    unsigned short* __restrict__ R0) {
  __shared__ __align__(16) unsigned short xs[26880];  // [42 ll][16 w'][40 c pad]
  int bid = blockIdx.x;
  int lq = bid & 3, wt = (bid >> 2) & 31, b = bid >> 7;
  int l0 = lq * 42, w0 = wt * 16;
  int tid = threadIdx.x, wv = tid >> 6, lane = tid & 63;
  int l15 = lane & 15, hi = lane >> 4;

  // stage x[b][:][w0..w0+16)[l0..l0+42) -> xs (coalesced reads, swizzled 2B writes)
  #pragma unroll 4
  for (int e = 0; e < 84; ++e) {
    int id = e * 256 + tid;
    int c = id / 672, rem = id - c * 672;
    int w = rem / 42, ll = rem - w * 42;
    float v = x[(size_t)((b * 32 + c) * 512 + w0 + w) * 168 + l0 + ll];
    xs[(ll * 16 + (w ^ (ll & 15))) * 40 + c] = f2bf(v);
  }
  __syncthreads();

  short8 uF[10];
  #pragma unroll
  for (int mt = 0; mt < 10; ++mt)
    uF[mt] = *(const short8*)(Ub + (size_t)(mt * 16 + l15) * 32 + hi * 8);

  for (int i = 0; i < 11; ++i) {
    int li = wv + 4 * i;
    if (li >= 42) break;
    int l = l0 + li;
    short8 xf = *(const short8*)&xs[(li * 16 + (l15 ^ (li & 15))) * 40 + hi * 8];
    size_t jbase = (size_t)(b * 168 + l) * 32;
    #pragma unroll
    for (int mt = 0; mt < 10; ++mt) {
      f32x4 z = {0.f, 0.f, 0.f, 0.f};
      f32x4 p = __builtin_amdgcn_mfma_f32_16x16x32_bf16(xf, uF[mt], z, 0, 0, 0);
      size_t jj = jbase + ((mt & 1) << 4) + l15;
      if (mt < 8) {
        int slice = mt >> 1;                       // w-local = hi*4 + r, chunk = slice*32+wt
        unsigned int pk = pack4fp8(p[0], p[1], p[2], p[3]);
        *(unsigned int*)(Pgf + ((size_t)(slice * 32 + wt) * NJ + jj) * 16 + hi * 4) = pk;
      } else {
        int r0c = wt * 2 + (hi >> 1);              // n-chunk; offset (hi&1)*4 + r
        u16x4 pk16 = { f2bf(p[0]), f2bf(p[1]), f2bf(p[2]), f2bf(p[3]) };
        *(u16x4*)(R0 + ((size_t)r0c * NJ + jj) * 8 + (hi & 1) * 4) = pk16;
      }
    }
  }
}

// ---- main GEMM (r9b schedule, fp8 operands): C = (G*64)fp8 * Pfp8, epilogue /64 ----
// BM=256 BN=128 BK=32, 256 threads = 4 waves (2M x 2N), wave tile 128x64.
// TRIPLE-buffered LDS (36KB): one counted vmcnt(3) + one s_barrier per K-tile.
// Staging 12KB/tile (half of bf16); ds_read_b64 fragments (half port time).
__global__ __launch_bounds__(256, 2) void gc_gemm9c(const unsigned char* __restrict__ G2f,
    const unsigned char* __restrict__ Pgf, const unsigned short* __restrict__ R0,
    const float* __restrict__ bias, float* __restrict__ out) {
  int bid = blockIdx.x;
  int swz = (bid & 7) * 84 + (bid >> 3);   // XCD-chunked bijective swizzle (672 = 8*84)
  int mt = swz & 1, jt = swz >> 1;         // mt fastest: B-panel pair adjacent on same XCD
  int n0 = mt * 256, jj0 = jt * 128;

  __shared__ __align__(16) unsigned char SH[36864];    // 36 KB
  unsigned char* AbBase = SH;              // 3 bufs x [kb2 2][n 256][16] = 3 x 8192
  unsigned char* BbBase = SH + 24576;      // 3 bufs x [kb2 2][j 128][16] = 3 x 4096

  int tid = threadIdx.x, lane = tid & 63, wid = tid >> 6;
  int wm = wid >> 1, wn = wid & 1;
  int l15 = lane & 15, hi = lane >> 4;

  const unsigned char* srcA[2]; int dA[2];
  #pragma unroll
  for (int q = 0; q < 2; ++q) {
    int f = q * 256 + tid;                       // kb2 = f>>8, nloc = f&255
    srcA[q] = G2f + ((size_t)(f >> 8) * 512 + n0 + (f & 255)) * 16;
    dA[q] = f * 16;
  }
  int g = tid;                                   // kb2 = g>>7, jloc = g&127
  const unsigned char* srcB0 = Pgf + ((size_t)(g >> 7) * NJ + jj0 + (g & 127)) * 16;
  int dB0 = g * 16;
  const size_t strideA = 2 * 512 * 16;           // bytes per K-32 tile (2 chunk rows)
  const size_t strideB = (size_t)2 * NJ * 16;

  f32x4 acc[8][4] = {};

  // prologue: tiles 0 -> buf0, 1 -> buf1 (6 loads in flight)
  #pragma unroll
  for (int q = 0; q < 2; ++q) gload_lds16(srcA[q], AbBase + dA[q]);
  gload_lds16(srcB0, BbBase + dB0);
  #pragma unroll
  for (int q = 0; q < 2; ++q) gload_lds16(srcA[q] + strideA, AbBase + 8192 + dA[q]);
  gload_lds16(srcB0 + strideB, BbBase + 4096 + dB0);

  int aoffs = (hi >> 1) * 4096 + (wm * 128 + l15) * 16 + (hi & 1) * 8;
  int boffs = (hi >> 1) * 2048 + (wn * 64 + l15) * 16 + (hi & 1) * 8;

  int cur = 0;
  for (int t = 0; t < 64; ++t) {
    if (t < 63) { asm volatile("s_waitcnt vmcnt(3)" ::: "memory"); }
    else        { asm volatile("s_waitcnt vmcnt(0)" ::: "memory"); }
    __builtin_amdgcn_s_barrier();                // tile t (buf[cur]) staged by all waves

    if (t < 62) {                                // stage t+2 into buffer of tile t-1
      int nxt = cur - 1; if (nxt < 0) nxt = 2;
      #pragma unroll
      for (int q = 0; q < 2; ++q)
        gload_lds16(srcA[q] + (size_t)(t + 2) * strideA, AbBase + nxt * 8192 + dA[q]);
      gload_lds16(srcB0 + (size_t)(t + 2) * strideB, BbBase + nxt * 4096 + dB0);
    }

    const unsigned char* ap = AbBase + cur * 8192;
    const unsigned char* bp = BbBase + cur * 4096;
    long aF[8]; long bF[4];
    #pragma unroll
    for (int mi = 0; mi < 8; ++mi)
      aF[mi] = *(const long*)(ap + aoffs + mi * 256);
    #pragma unroll
    for (int nj = 0; nj < 4; ++nj)
      bF[nj] = *(const long*)(bp + boffs + nj * 256);

    #pragma unroll
    for (int mi = 0; mi < 8; ++mi)
      #pragma unroll
      for (int nj = 0; nj < 4; ++nj)
        acc[mi][nj] = __builtin_amdgcn_mfma_f32_16x16x32_fp8_fp8(aF[mi], bF[nj], acc[mi][nj], 0, 0, 0);

    cur = cur + 1; if (cur == 3) cur = 0;
  }

  // ---- epilogue: 4 slabs of 64 n; LDS transpose; out = C/64 + R0 + bias ----
  int bl0 = jt * 4;                              // 4 consecutive (b,l), same b (168%4==0)
  int bq = bl0 / 168, l0g = bl0 - bq * 168;
  float* Cs = (float*)SH;                        // 64*132*4 = 33792 B <= 36864
  int o = tid & 31, nl8 = tid >> 5;              // o 0..31, nl8 0..7
  float bs = bias[o];
  __syncthreads();
  for (int s = 0; s < 4; ++s) {
    if (wm == (s >> 1)) {
      int mio = (s & 1) * 4;
      #pragma unroll
      for (int mi = 0; mi < 4; ++mi)
        #pragma unroll
        for (int nj = 0; nj < 4; ++nj) {
          int row = mi * 16 + hi * 4;
          int col = wn * 64 + nj * 16 + l15;
          #pragma unroll
          for (int r = 0; r < 4; ++r)
            Cs[(row + r) * 132 + col] = acc[mio + mi][nj][r] * 0.015625f;   // /64 prescale
        }
    }
    __syncthreads();
    int n_g0 = n0 + s * 64 + nl8 * 8;
    const unsigned short* p4c =
        R0 + ((size_t)(n_g0 >> 3) * NJ + (size_t)bl0 * 32 + o) * 8;
    short8 pv0 = *(const short8*)(p4c);
    short8 pv1 = *(const short8*)(p4c + 256);    // l+1 (jj stride 32 chunks)
    short8 pv2 = *(const short8*)(p4c + 512);    // l+2
    short8 pv3 = *(const short8*)(p4c + 768);    // l+3
    #pragma unroll
    for (int q = 0; q < 8; ++q) {
      int nr = nl8 * 8 + q;
      int n_g = n_g0 + q;
      float v0 = Cs[nr * 132 +  0 + o] + bf2f((unsigned short)pv0[q]) + bs;
      float v1 = Cs[nr * 132 + 32 + o] + bf2f((unsigned short)pv1[q]) + bs;
      float v2 = Cs[nr * 132 + 64 + o] + bf2f((unsigned short)pv2[q]) + bs;
      float v3 = Cs[nr * 132 + 96 + o] + bf2f((unsigned short)pv3[q]) + bs;
      f32x4 vv = {v0, v1, v2, v3};
      *(f32x4*)(out + ((size_t)(bq * 32 + o) * 512 + n_g) * 168 + l0g) = vv;
    }
    __syncthreads();
  }
}

extern "C" void kernel_launch(void* const* d_in, const int* in_sizes, int n_in,
                              void* d_out, int out_size, void* d_ws, size_t ws_size,
                              hipStream_t stream) {
  const float* x   = (const float*)d_in[0];
  const float* adp = (const float*)d_in[1];
  const float* W1  = (const float*)d_in[2];
  const float* b1  = (const float*)d_in[3];
  const float* W2  = (const float*)d_in[4];
  const float* b2  = (const float*)d_in[5];
  float* out = (float*)d_out;

  char* w = (char*)d_ws;
  unsigned char*  Pgf = (unsigned char*)(w);                   //  88,080,384 B (4 fp8 slices)
  unsigned short* R0  = (unsigned short*)(w + 88080384ULL);    //  44,040,192 B (bf16 residual)
  unsigned char*  G2f = (unsigned char*)(w + 132120576ULL);    //   1,048,576 B (fp8, x64)
  float* Af           = (float*)(w + 133169152ULL);            //   2,097,152 B
  unsigned short* Ub  = (unsigned short*)(w + 135266304ULL);   //      16,384 B (10,240 used)
  float* bias         = (float*)(w + 135282688ULL);            //         128 B
  if (ws_size < 135282816ULL) return;                          // need ~129 MiB

  gc_prep2<<<513, 256, 0, stream>>>(adp, W1, b1, W2, b2, Af, G2f, Ub, bias);
  gc_sq2<<<512, 256, 0, stream>>>(Af, G2f);
  gc_mix6<<<1024, 256, 0, stream>>>(x, Ub, Pgf, R0);
  gc_gemm9c<<<672, 256, 0, stream>>>(G2f, Pgf, R0, bias, out);
}

// Round 18
// 172.717 us; speedup vs baseline: 1.7785x; 1.1428x over previous
//
#include <hip/hip_runtime.h>
#include <stdint.h>

// Problem dims
#define BDIM 8
#define CDIM 32
#define NDIM 512
#define TDIM 168
#define KG   2048          // GEMM K = 4 slices * 512 nodes
#define NJ   43008         // 1344 (b,l) * 32 o   (column order jj = (b*168+l)*32 + o)
#define ALPHA_ 0.05f
#define BETA_  0.95f

typedef __attribute__((ext_vector_type(8))) short short8;
typedef __attribute__((ext_vector_type(4))) float f32x4;
typedef __attribute__((ext_vector_type(16))) float f32x16;
typedef __attribute__((ext_vector_type(2))) float f2v;
typedef __attribute__((ext_vector_type(4))) unsigned short u16x4;
typedef __attribute__((ext_vector_type(4))) int i32x4;
typedef __attribute__((ext_vector_type(8))) int i32x8;

__device__ __forceinline__ unsigned short f2bf(float f) {
  union { float f; unsigned int u; } v; v.f = f;
  unsigned int r = v.u + 0x7fffu + ((v.u >> 16) & 1u);
  return (unsigned short)(r >> 16);
}
__device__ __forceinline__ float bf2f(unsigned short h) {
  union { unsigned int u; float f; } v; v.u = ((unsigned int)h) << 16;
  return v.f;
}
// OCP e4m3fn software encoder (RNE in normal range; used by prep/sq, fallback for mix)
__device__ __forceinline__ unsigned char f2fp8(float f) {
  union { float f; unsigned u; } v; v.f = f;
  unsigned s = (v.u >> 24) & 0x80u;
  unsigned au = v.u & 0x7fffffffu;
  if (au >= 0x43e80000u) return (unsigned char)(s | 0x7eu);   // >= 464 -> clamp to 448
  if (au < 0x3c800000u) {                                     // < 2^-6: subnormal (step 2^-9)
    float a = (f < 0.f) ? -f : f;
    unsigned m = (unsigned)(a * 512.f + 0.5f);
    return (unsigned char)(s | (m > 7 ? 8u : m));
  }
  unsigned e8 = au >> 23;
  unsigned m23 = au & 0x7fffffu;
  unsigned rm = m23 + 0x7ffffu + ((m23 >> 20) & 1u);
  if (rm >= 0x800000u) { rm -= 0x800000u; e8 += 1u; }
  unsigned e4 = e8 - 120u;                                    // in [1,15]
  return (unsigned char)(s | (e4 << 3) | (rm >> 20));
}
__device__ __forceinline__ unsigned int pack4fp8(float a, float b, float c, float d) {
#if __has_builtin(__builtin_amdgcn_cvt_pk_fp8_f32)
  int r = __builtin_amdgcn_cvt_pk_fp8_f32(a, b, 0, false);
  r = __builtin_amdgcn_cvt_pk_fp8_f32(c, d, r, true);
  return (unsigned int)r;
#else
  return (unsigned)f2fp8(a) | ((unsigned)f2fp8(b) << 8) |
         ((unsigned)f2fp8(c) << 16) | ((unsigned)f2fp8(d) << 24);
#endif
}
__device__ __forceinline__ void gload_lds16(const void* g, void* l) {
  __builtin_amdgcn_global_load_lds((const __attribute__((address_space(1))) void*)g,
                                   (__attribute__((address_space(3))) void*)l, 16, 0, 0);
}

// ---- fused prep+build (+ucat in block 512): G2f = fp8(A|A' * 64), chunks [k>>4][n][16] ----
__global__ void gc_prep2(const float* __restrict__ adp,
                         const float* __restrict__ W1, const float* __restrict__ b1,
                         const float* __restrict__ W2, const float* __restrict__ b2,
                         float* __restrict__ Af, unsigned char* __restrict__ G2f,
                         unsigned short* __restrict__ Ub, float* __restrict__ bias) {
  int t = threadIdx.x;
  if (blockIdx.x == 512) {   // ucat
    for (int idx = t; idx < 160 * 32; idx += 256) {
      int ko = idx >> 5, c = idx & 31, o = ko & 31, s = ko >> 5;
      float v;
      if (s == 0)      v = BETA_ * (W1[o * 96 + 32 + c] + ALPHA_ * W1[o * 96 + 64 + c]);
      else if (s == 1) v = BETA_ * BETA_ * W1[o * 96 + 64 + c];
      else if (s == 2) v = BETA_ * (W2[o * 96 + 32 + c] + ALPHA_ * W2[o * 96 + 64 + c]);
      else if (s == 3) v = BETA_ * BETA_ * W2[o * 96 + 64 + c];
      else             v = W1[o * 96 + c] + ALPHA_ * (W1[o * 96 + 32 + c] + W1[o * 96 + 64 + c])
                         + W2[o * 96 + c] + ALPHA_ * (W2[o * 96 + 32 + c] + W2[o * 96 + 64 + c]);
      Ub[idx] = f2bf(v);
    }
    if (t < 32) bias[t] = b1[t] + b2[t];
    return;
  }
  int v = blockIdx.x;
  float sA = 0.f, sB = 0.f;
  for (int w = t; w < NDIM; w += 256) { sA += adp[v * NDIM + w]; sB += adp[w * NDIM + v]; }
  __shared__ float red[2][256];
  red[0][t] = sA; red[1][t] = sB; __syncthreads();
  for (int s = 128; s > 0; s >>= 1) {
    if (t < s) { red[0][t] += red[0][t + s]; red[1][t] += red[1][t + s]; }
    __syncthreads();
  }
  float ra = 1.f / (1.f + red[0][0]);
  float rb = 1.f / (1.f + red[1][0]);
  for (int w = t; w < NDIM; w += 256) {
    float d = (v == w) ? 1.f : 0.f;
    float a  = (adp[v * NDIM + w] + d) * ra;   // A[v][w]
    float a2 = (adp[w * NDIM + v] + d) * rb;   // A'[v][w]
    Af[(size_t)v * NDIM + w] = a;
    Af[(size_t)NDIM * NDIM + (size_t)v * NDIM + w] = a2;
    // slice 0 chunks [0,32), slice 2 chunks [64,96); prescale x64 (undone in GEMM epilogue)
    G2f[((size_t)((0  + (w >> 4)) * 512) + v) * 16 + (w & 15)] = f2fp8(a * 64.f);
    G2f[((size_t)((64 + (w >> 4)) * 512) + v) * 16 + (w & 15)] = f2fp8(a2 * 64.f);
  }
}

// ---- A^2 (slice 1, chunks [32,64)) and A'^2 (slice 3, chunks [96,128)) into G2f ----
__global__ __launch_bounds__(256, 4) void gc_sq2(const float* __restrict__ Af,
                                                 unsigned char* __restrict__ G2f) {
  int bid = blockIdx.x;
  int mat = bid >> 8, tile = bid & 255;
  int v0 = (tile >> 4) * 32, w0 = (tile & 15) * 32;
  const float* M = Af + (size_t)mat * NDIM * NDIM;
  __shared__ float T1[64][33];
  __shared__ float T2[64][33];
  int t = threadIdx.x;
  int ty = t >> 4, tx = t & 15;
  float a00 = 0.f, a01 = 0.f, a10 = 0.f, a11 = 0.f;
  for (int u0 = 0; u0 < NDIM; u0 += 64) {
    #pragma unroll
    for (int q = 0; q < 8; ++q) {
      int id = q * 256 + t;
      int c = id & 63, r = id >> 6;
      T1[c][r] = M[(size_t)(v0 + r) * NDIM + u0 + c];
      int u = id >> 5, w = id & 31;
      T2[u][w] = M[(size_t)(u0 + u) * NDIM + w0 + w];
    }
    __syncthreads();
    for (int u = 0; u < 64; ++u) {
      f2v a = *(const f2v*)&T1[u][ty * 2];
      f2v b = *(const f2v*)&T2[u][tx * 2];
      a00 += a[0] * b[0]; a01 += a[0] * b[1];
      a10 += a[1] * b[0]; a11 += a[1] * b[1];
    }
    __syncthreads();
  }
  int base = mat ? 96 : 32;                    // slice 1 or 3 chunk base
  int v = v0 + ty * 2, w = w0 + tx * 2;
  size_t cb  = (size_t)((base + (w >> 4)) * 512) * 16;
  size_t cb1 = (size_t)((base + ((w + 1) >> 4)) * 512) * 16;
  G2f[cb  + (size_t)(v    ) * 16 + (w & 15)]       = f2fp8(a00 * 64.f);
  G2f[cb1 + (size_t)(v    ) * 16 + ((w + 1) & 15)] = f2fp8(a01 * 64.f);
  G2f[cb  + (size_t)(v + 1) * 16 + (w & 15)]       = f2fp8(a10 * 64.f);
  G2f[cb1 + (size_t)(v + 1) * 16 + ((w + 1) & 15)] = f2fp8(a11 * 64.f);
}

// ---- channel-mix via MFMA: fp8 Pgf (slices 0..3) + bf16 R0 (identity residual) ----
// Pgf[c16 0..128)[jj][16 fp8], c16 = slice*32 + (w>>4); R0[c8 0..64)[jj][8 bf16].
// grid 1024 = 8 b * 32 wt(16 w) * 4 lq(42 l); 256 threads (4 waves)
__global__ __launch_bounds__(256, 2) void gc_mix6(const float* __restrict__ x,
    const unsigned short* __restrict__ Ub, unsigned char* __restrict__ Pgf,
    unsigned short* __restrict__ R0) {
  __shared__ __align__(16) unsigned short xs[26880];  // [42 ll][16 w'][40 c pad]
  int bid = blockIdx.x;
  int lq = bid & 3, wt = (bid >> 2) & 31, b = bid >> 7;
  int l0 = lq * 42, w0 = wt * 16;
  int tid = threadIdx.x, wv = tid >> 6, lane = tid & 63;
  int l15 = lane & 15, hi = lane >> 4;

  // stage x[b][:][w0..w0+16)[l0..l0+42) -> xs (coalesced reads, swizzled 2B writes)
  #pragma unroll 4
  for (int e = 0; e < 84; ++e) {
    int id = e * 256 + tid;
    int c = id / 672, rem = id - c * 672;
    int w = rem / 42, ll = rem - w * 42;
    float v = x[(size_t)((b * 32 + c) * 512 + w0 + w) * 168 + l0 + ll];
    xs[(ll * 16 + (w ^ (ll & 15))) * 40 + c] = f2bf(v);
  }
  __syncthreads();

  short8 uF[10];
  #pragma unroll
  for (int mt = 0; mt < 10; ++mt)
    uF[mt] = *(const short8*)(Ub + (size_t)(mt * 16 + l15) * 32 + hi * 8);

  for (int i = 0; i < 11; ++i) {
    int li = wv + 4 * i;
    if (li >= 42) break;
    int l = l0 + li;
    short8 xf = *(const short8*)&xs[(li * 16 + (l15 ^ (li & 15))) * 40 + hi * 8];
    size_t jbase = (size_t)(b * 168 + l) * 32;
    #pragma unroll
    for (int mt = 0; mt < 10; ++mt) {
      f32x4 z = {0.f, 0.f, 0.f, 0.f};
      f32x4 p = __builtin_amdgcn_mfma_f32_16x16x32_bf16(xf, uF[mt], z, 0, 0, 0);
      size_t jj = jbase + ((mt & 1) << 4) + l15;
      if (mt < 8) {
        int slice = mt >> 1;                       // w-local = hi*4 + r, chunk = slice*32+wt
        unsigned int pk = pack4fp8(p[0], p[1], p[2], p[3]);
        *(unsigned int*)(Pgf + ((size_t)(slice * 32 + wt) * NJ + jj) * 16 + hi * 4) = pk;
      } else {
        int r0c = wt * 2 + (hi >> 1);              // n-chunk; offset (hi&1)*4 + r
        u16x4 pk16 = { f2bf(p[0]), f2bf(p[1]), f2bf(p[2]), f2bf(p[3]) };
        *(u16x4*)(R0 + ((size_t)r0c * NJ + jj) * 8 + (hi & 1) * 4) = pk16;
      }
    }
  }
}

// ---- main GEMM: MX-scaled fp8, K=64 tiles (mfma_scale_f32_32x32x64_f8f6f4, scale=1) ----
// BM=256 BN=128 BK=64, 256 threads = 4 waves (2M x 2N), wave tile 128x64 = 4x2 MFMAs.
// TRIPLE-buffered LDS (72KB, 2 blocks/CU): one counted vmcnt(6) + one barrier/K-tile.
// Fragments are 32B/lane -> ds_read_b128 pairs at stride 16 (conflict-free).
__global__ __launch_bounds__(256, 2) void gc_gemm15(const unsigned char* __restrict__ G2f,
    const unsigned char* __restrict__ Pgf, const unsigned short* __restrict__ R0,
    const float* __restrict__ bias, float* __restrict__ out) {
  int bid = blockIdx.x;
  int swz = (bid & 7) * 84 + (bid >> 3);   // XCD-chunked bijective swizzle (672 = 8*84)
  int mt = swz & 1, jt = swz >> 1;         // mt fastest: B-panel pair adjacent on same XCD
  int n0 = mt * 256, jj0 = jt * 128;

  __shared__ __align__(16) unsigned char SH[73728];    // 72 KB
  unsigned char* AbBase = SH;              // 3 bufs x [kb4 4][n 256][16] = 3 x 16384
  unsigned char* BbBase = SH + 49152;      // 3 bufs x [kb4 4][j 128][16] = 3 x 8192

  int tid = threadIdx.x, lane = tid & 63, wid = tid >> 6;
  int wm = wid >> 1, wn = wid & 1;
  int lo = lane & 31, hs = lane >> 5;

  // staging assignments (16B chunks per K-64 tile): A 4 rounds, B 2 rounds
  const unsigned char* srcA[4]; int dA[4];
  #pragma unroll
  for (int q = 0; q < 4; ++q) {                  // kb4 = q, n = tid
    srcA[q] = G2f + ((size_t)(q * 512) + n0 + tid) * 16;
    dA[q] = (q * 256 + tid) * 16;
  }
  const unsigned char* srcB[2]; int dB[2];
  #pragma unroll
  for (int q = 0; q < 2; ++q) {
    int g = q * 256 + tid;                       // kb4 = g>>7, jloc = g&127
    srcB[q] = Pgf + ((size_t)(g >> 7) * NJ + jj0 + (g & 127)) * 16;
    dB[q] = g * 16;
  }
  const size_t strideA = 4 * 512 * 16;           // bytes per K-64 tile
  const size_t strideB = (size_t)4 * NJ * 16;

  f32x16 acc[4][2] = {};

  // prologue: tiles 0 -> buf0, 1 -> buf1 (12 loads in flight)
  #pragma unroll
  for (int q = 0; q < 4; ++q) gload_lds16(srcA[q], AbBase + dA[q]);
  #pragma unroll
  for (int q = 0; q < 2; ++q) gload_lds16(srcB[q], BbBase + dB[q]);
  #pragma unroll
  for (int q = 0; q < 4; ++q) gload_lds16(srcA[q] + strideA, AbBase + 16384 + dA[q]);
  #pragma unroll
  for (int q = 0; q < 2; ++q) gload_lds16(srcB[q] + strideB, BbBase + 8192 + dB[q]);

  int aoffs = hs * 8192 + (wm * 128 + lo) * 16;  // + mi*512 ; second chunk +4096
  int boffs = hs * 4096 + (wn * 64 + lo) * 16;   // + nj*512 ; second chunk +2048

  int cur = 0;
  for (int t = 0; t < 32; ++t) {
    if (t < 31) { asm volatile("s_waitcnt vmcnt(6)" ::: "memory"); }
    else        { asm volatile("s_waitcnt vmcnt(0)" ::: "memory"); }
    __builtin_amdgcn_s_barrier();                // tile t (buf[cur]) staged by all waves

    if (t < 30) {                                // stage t+2 into buffer of tile t-1
      int nxt = cur - 1; if (nxt < 0) nxt = 2;
      #pragma unroll
      for (int q = 0; q < 4; ++q)
        gload_lds16(srcA[q] + (size_t)(t + 2) * strideA, AbBase + nxt * 16384 + dA[q]);
      #pragma unroll
      for (int q = 0; q < 2; ++q)
        gload_lds16(srcB[q] + (size_t)(t + 2) * strideB, BbBase + nxt * 8192 + dB[q]);
    }

    const unsigned char* ap = AbBase + cur * 16384;
    const unsigned char* bp = BbBase + cur * 8192;
    i32x8 aF[4], bF[2];
    #pragma unroll
    for (int mi = 0; mi < 4; ++mi) {
      i32x4 alo = *(const i32x4*)(ap + aoffs + mi * 512);
      i32x4 ahi = *(const i32x4*)(ap + aoffs + mi * 512 + 4096);
      aF[mi] = __builtin_shufflevector(alo, ahi, 0, 1, 2, 3, 4, 5, 6, 7);
    }
    #pragma unroll
    for (int nj = 0; nj < 2; ++nj) {
      i32x4 blo = *(const i32x4*)(bp + boffs + nj * 512);
      i32x4 bhi = *(const i32x4*)(bp + boffs + nj * 512 + 2048);
      bF[nj] = __builtin_shufflevector(blo, bhi, 0, 1, 2, 3, 4, 5, 6, 7);
    }

    #pragma unroll
    for (int mi = 0; mi < 4; ++mi)
      #pragma unroll
      for (int nj = 0; nj < 2; ++nj)
        acc[mi][nj] = __builtin_amdgcn_mfma_scale_f32_32x32x64_f8f6f4(
            aF[mi], bF[nj], acc[mi][nj], 0, 0, 0, 0x7F7F7F7F, 0, 0x7F7F7F7F);

    cur = cur + 1; if (cur == 3) cur = 0;
  }

  // ---- epilogue: 4 slabs of 64 n; LDS transpose; out = C/64 + R0 + bias ----
  // 32x32 C/D layout: col = lane&31, row = (reg&3) + 8*(reg>>2) + 4*(lane>>5)
  int bl0 = jt * 4;                              // 4 consecutive (b,l), same b (168%4==0)
  int bq = bl0 / 168, l0g = bl0 - bq * 168;
  float* Cs = (float*)SH;                        // 64*132*4 = 33792 B <= 72KB
  int o = tid & 31, nl8 = tid >> 5;              // o 0..31, nl8 0..7
  float bs = bias[o];
  __syncthreads();
  for (int s = 0; s < 4; ++s) {
    if (wm == (s >> 1)) {
      int mib = (s & 1) * 2;
      #pragma unroll
      for (int mi2 = 0; mi2 < 2; ++mi2)
        #pragma unroll
        for (int nj = 0; nj < 2; ++nj) {
          int col = wn * 64 + nj * 32 + lo;
          #pragma unroll
          for (int r = 0; r < 16; ++r) {
            int row = mi2 * 32 + (r & 3) + 8 * (r >> 2) + 4 * hs;
            Cs[row * 132 + col] = acc[mib + mi2][nj][r] * 0.015625f;   // /64 prescale
          }
        }
    }
    __syncthreads();
    int n_g0 = n0 + s * 64 + nl8 * 8;
    const unsigned short* p4c =
        R0 + ((size_t)(n_g0 >> 3) * NJ + (size_t)bl0 * 32 + o) * 8;
    short8 pv0 = *(const short8*)(p4c);
    short8 pv1 = *(const short8*)(p4c + 256);    // l+1 (jj stride 32 chunks)
    short8 pv2 = *(const short8*)(p4c + 512);    // l+2
    short8 pv3 = *(const short8*)(p4c + 768);    // l+3
    #pragma unroll
    for (int q = 0; q < 8; ++q) {
      int nr = nl8 * 8 + q;
      int n_g = n_g0 + q;
      float v0 = Cs[nr * 132 +  0 + o] + bf2f((unsigned short)pv0[q]) + bs;
      float v1 = Cs[nr * 132 + 32 + o] + bf2f((unsigned short)pv1[q]) + bs;
      float v2 = Cs[nr * 132 + 64 + o] + bf2f((unsigned short)pv2[q]) + bs;
      float v3 = Cs[nr * 132 + 96 + o] + bf2f((unsigned short)pv3[q]) + bs;
      f32x4 vv = {v0, v1, v2, v3};
      *(f32x4*)(out + ((size_t)(bq * 32 + o) * 512 + n_g) * 168 + l0g) = vv;
    }
    __syncthreads();
  }
}

extern "C" void kernel_launch(void* const* d_in, const int* in_sizes, int n_in,
                              void* d_out, int out_size, void* d_ws, size_t ws_size,
                              hipStream_t stream) {
  const float* x   = (const float*)d_in[0];
  const float* adp = (const float*)d_in[1];
  const float* W1  = (const float*)d_in[2];
  const float* b1  = (const float*)d_in[3];
  const float* W2  = (const float*)d_in[4];
  const float* b2  = (const float*)d_in[5];
  float* out = (float*)d_out;

  char* w = (char*)d_ws;
  unsigned char*  Pgf = (unsigned char*)(w);                   //  88,080,384 B (4 fp8 slices)
  unsigned short* R0  = (unsigned short*)(w + 88080384ULL);    //  44,040,192 B (bf16 residual)
  unsigned char*  G2f = (unsigned char*)(w + 132120576ULL);    //   1,048,576 B (fp8, x64)
  float* Af           = (float*)(w + 133169152ULL);            //   2,097,152 B
  unsigned short* Ub  = (unsigned short*)(w + 135266304ULL);   //      16,384 B (10,240 used)
  float* bias         = (float*)(w + 135282688ULL);            //         128 B
  if (ws_size < 135282816ULL) return;                          // need ~129 MiB

  gc_prep2<<<513, 256, 0, stream>>>(adp, W1, b1, W2, b2, Af, G2f, Ub, bias);
  gc_sq2<<<512, 256, 0, stream>>>(Af, G2f);
  gc_mix6<<<1024, 256, 0, stream>>>(x, Ub, Pgf, R0);
  gc_gemm15<<<672, 256, 0, stream>>>(G2f, Pgf, R0, bias, out);
}